// Round 1
// 168.384 us; speedup vs baseline: 1.0633x; 1.0633x over previous
//
#include <hip/hip_runtime.h>

#define Bn 2
#define Hn 16
#define Tn 2048
#define Sn 2048
#define Wd 1024
#define Dh 64

typedef __attribute__((ext_vector_type(8))) short s16x8;
typedef __attribute__((ext_vector_type(4))) short s16x4;
typedef __attribute__((ext_vector_type(4))) float f32x4;
typedef __attribute__((ext_vector_type(2))) unsigned u32x2;

#define MFMA(a, b, c) __builtin_amdgcn_mfma_f32_16x16x32_bf16((a), (b), (c), 0, 0, 0)

__device__ __forceinline__ s16x8 ld8(const short* p) { return *(const s16x8*)p; }

// fp32 -> bf16 round-to-nearest-even
__device__ __forceinline__ short f2bf(float f) {
    unsigned u = __builtin_bit_cast(unsigned, f);
    u += 0x7FFFu + ((u >> 16) & 1u);
    return (short)(u >> 16);
}

// ---------------------------------------------------------------------------
// fp32 -> bf16 bulk convert with scale (8 elems/thread, coalesced)
// ---------------------------------------------------------------------------
__global__ void cvt_scale(const float* __restrict__ in, short* __restrict__ out,
                          int n, float s) {
    int i = (blockIdx.x * 256 + threadIdx.x) * 8;
    if (i < n) {
        float4 a = *(const float4*)(in + i);
        float4 b = *(const float4*)(in + i + 4);
        s16x8 o;
        o[0] = f2bf(a.x * s); o[1] = f2bf(a.y * s); o[2] = f2bf(a.z * s); o[3] = f2bf(a.w * s);
        o[4] = f2bf(b.x * s); o[5] = f2bf(b.y * s); o[6] = f2bf(b.z * s); o[7] = f2bf(b.w * s);
        *(s16x8*)(out + i) = o;
    }
}

// ---------------------------------------------------------------------------
// V -> V^T bf16 with s-position permutation matched to attn's b64 P packing:
// position p (0..63 within each 64-chunk) holds s = (p&3)*16 + (p>>2)
// (dot products are k-order invariant as long as P and V^T agree).
// vt[(b*16+h)*64+d][pos].  64x64 tiles via LDS.
// ---------------------------------------------------------------------------
__global__ __launch_bounds__(256) void vtrans(const float* __restrict__ cv,
                                              short* __restrict__ vt) {
    __shared__ short T[64][68];
    const int st = blockIdx.x & 31;          // s tile (64 wide)
    const int bh = blockIdx.x >> 5;          // 0..31
    const int b = bh >> 4, h = bh & 15;
    const int tid = threadIdx.x;
#pragma unroll
    for (int i = 0; i < 4; ++i) {
        int f = i * 256 + tid, sr = f >> 4, c4 = f & 15;
        float4 v = *(const float4*)(cv + (size_t)(b * Sn + st * 64 + sr) * Wd + h * Dh + c4 * 4);
        s16x4 o;
        o[0] = f2bf(v.x); o[1] = f2bf(v.y); o[2] = f2bf(v.z); o[3] = f2bf(v.w);
        *(s16x4*)&T[sr][c4 * 4] = o;
    }
    __syncthreads();
#pragma unroll
    for (int i = 0; i < 4; ++i) {
        int f = i * 256 + tid, dr = f >> 4, p4 = f & 15;
        s16x4 o;
#pragma unroll
        for (int k = 0; k < 4; ++k) {
            // p = p4*4 + k  ->  s-local = (p&3)*16 + (p>>2) = k*16 + p4
            o[k] = T[k * 16 + p4][dr];
        }
        *(s16x4*)(vt + (size_t)(bh * Dh + dr) * Sn + st * 64 + p4 * 4) = o;
    }
}

#define KSTR 72   // K/V/P LDS row stride in shorts (144 B = 9*16: b128-aligned,
                  // 4-bank row rotation -> 2 lanes/bank on b128 reads)

// ---------------------------------------------------------------------------
// Attention, double-buffered K/V tiles + async reg-staged prefetch (T14):
// per 64-S chunk: issue next chunk's global ld8s -> QK (MFMA) -> exp2/pack ->
// P via per-wave LDS (b64 writes, b128 reads) -> PV (MFMA) -> write prefetched
// regs to the alternate LDS buffer -> ONE __syncthreads.
// Global-load latency hides under ~1.5k cy of compute; barrier count halved.
// P packing: row = q, position p = l16*4 + sj  (s = (p&3)*16 + (p>>2)),
// matching vtrans.  b64 P writes: each 32-lane half hits 32 distinct banks.
// Grid 512, blk%8 = bh%8 -> XCD L2 locality.
// ---------------------------------------------------------------------------
__global__ __launch_bounds__(256, 2) void attn_fused(
    const float* __restrict__ x, const short* __restrict__ kb,
    const short* __restrict__ vt, short* __restrict__ ao)
{
    __shared__ alignas(16) short Ks[2][64 * KSTR];   // 18.4 KB
    __shared__ alignas(16) short Vs[2][64 * KSTR];   // 18.4 KB
    __shared__ alignas(16) short Pt[4][32 * KSTR];   // 18.4 KB (per-wave P tiles)

    const int tid  = threadIdx.x;
    const int w    = tid >> 6;
    const int l    = tid & 63;
    const int quad = l >> 4;
    const int l16  = l & 15;

    const int bh = blockIdx.x & 31;          // blk%8 = bh%8 -> XCD locality
    const int qt = blockIdx.x >> 5;
    const int b  = bh >> 4, h = bh & 15;

    const int qrow0 = qt * 128 + w * 32;

    // Q A-frags from fp32, scaled by 0.125*log2e (folds 1/sqrt(d) and exp2 base)
    const float SQ = 0.125f * 1.4426950408889634f;
    s16x8 aq[2][2];
#pragma unroll
    for (int mi = 0; mi < 2; ++mi)
#pragma unroll
        for (int c = 0; c < 2; ++c) {
            const float* p = x + (size_t)(b * Tn + qrow0 + mi * 16 + l16) * Wd
                               + h * Dh + c * 32 + quad * 8;
            float4 a = ((const float4*)p)[0], bb = ((const float4*)p)[1];
            s16x8 o;
            o[0] = f2bf(a.x * SQ); o[1] = f2bf(a.y * SQ); o[2] = f2bf(a.z * SQ); o[3] = f2bf(a.w * SQ);
            o[4] = f2bf(bb.x * SQ); o[5] = f2bf(bb.y * SQ); o[6] = f2bf(bb.z * SQ); o[7] = f2bf(bb.w * SQ);
            aq[mi][c] = o;
        }

    f32x4 oacc[2][4];
    float dn[2][4];
#pragma unroll
    for (int mi = 0; mi < 2; ++mi) {
#pragma unroll
        for (int nt = 0; nt < 4; ++nt) {
            oacc[mi][nt][0] = 0.f; oacc[mi][nt][1] = 0.f;
            oacc[mi][nt][2] = 0.f; oacc[mi][nt][3] = 0.f;
        }
#pragma unroll
        for (int r = 0; r < 4; ++r) dn[mi][r] = 0.f;
    }

    const short* kb_h = kb + (size_t)(b * Sn) * Wd + h * Dh;
    const short* vt_h = vt + (size_t)(bh * Dh) * Sn;

    const int sr = tid >> 3;   // staging row 0..31 (two passes: +0, +32)
    const int sg = tid & 7;    // 16B segment 0..7 within a 128B row

    short* Pw = &Pt[w][0];

    // prologue: stage chunk 0 into buffer 0
    s16x8 kr[2], vr[2];
#pragma unroll
    for (int i = 0; i < 2; ++i) {
        int r0 = sr + i * 32;
        kr[i] = ld8(kb_h + (size_t)r0 * Wd + sg * 8);
        vr[i] = ld8(vt_h + (size_t)r0 * Sn + sg * 8);
    }
#pragma unroll
    for (int i = 0; i < 2; ++i) {
        int r0 = sr + i * 32;
        *(s16x8*)&Ks[0][r0 * KSTR + sg * 8] = kr[i];
        *(s16x8*)&Vs[0][r0 * KSTR + sg * 8] = vr[i];
    }
    __syncthreads();

    const int NIT = Sn / 64;
    for (int it = 0; it < NIT; ++it) {
        const int p = it & 1;

        // issue next chunk's global loads early (latency hides under compute)
        if (it + 1 < NIT) {
            const int s1 = (it + 1) * 64;
#pragma unroll
            for (int i = 0; i < 2; ++i) {
                int r0 = sr + i * 32;
                kr[i] = ld8(kb_h + (size_t)(s1 + r0) * Wd + sg * 8);
                vr[i] = ld8(vt_h + (size_t)r0 * Sn + s1 + sg * 8);
            }
        }

        // ---- QK: sc[mi][sj] over 64 s ----
        f32x4 sc[2][4];
        const f32x4 z = {0.f, 0.f, 0.f, 0.f};
        __builtin_amdgcn_s_setprio(1);
#pragma unroll
        for (int sj = 0; sj < 4; ++sj) {
            s16x8 k0 = *(const s16x8*)&Ks[p][(sj * 16 + l16) * KSTR + quad * 8];
            s16x8 k1 = *(const s16x8*)&Ks[p][(sj * 16 + l16) * KSTR + 32 + quad * 8];
#pragma unroll
            for (int mi = 0; mi < 2; ++mi) {
                sc[mi][sj] = MFMA(aq[mi][0], k0, z);
                sc[mi][sj] = MFMA(aq[mi][1], k1, sc[mi][sj]);
            }
        }
        __builtin_amdgcn_s_setprio(0);

        // ---- exp2, pack sj 0..3 into one b64 per (mi,r), write P ----
        // row = mi*16 + quad*4 + r, col shorts = l16*4; position p = l16*4+sj
#pragma unroll
        for (int mi = 0; mi < 2; ++mi)
#pragma unroll
            for (int r = 0; r < 4; ++r) {
                unsigned u0 = __builtin_bit_cast(unsigned, __builtin_amdgcn_exp2f(sc[mi][0][r]));
                unsigned u1 = __builtin_bit_cast(unsigned, __builtin_amdgcn_exp2f(sc[mi][1][r]));
                unsigned u2 = __builtin_bit_cast(unsigned, __builtin_amdgcn_exp2f(sc[mi][2][r]));
                unsigned u3 = __builtin_bit_cast(unsigned, __builtin_amdgcn_exp2f(sc[mi][3][r]));
                unsigned h1 = u1 & 0xFFFF0000u;
                unsigned h3 = u3 & 0xFFFF0000u;
                unsigned w0 = (u0 >> 16) | h1;
                unsigned w1 = (u2 >> 16) | h3;
                float t0 = __builtin_bit_cast(float, u0 & 0xFFFF0000u)
                         + __builtin_bit_cast(float, h1);
                float t1 = __builtin_bit_cast(float, u2 & 0xFFFF0000u)
                         + __builtin_bit_cast(float, h3);
                dn[mi][r] += t0 + t1;
                u32x2 pk; pk[0] = w0; pk[1] = w1;
                *(u32x2*)&Pw[(mi * 16 + quad * 4 + r) * KSTR + l16 * 4] = pk;
            }
        __asm__ __volatile__("" ::: "memory");   // keep LDS write->read order

        // ---- PV: oacc[mi][nt] += P[mi] x V^T ----
        s16x8 ap[2][2], bv[4][2];
#pragma unroll
        for (int mi = 0; mi < 2; ++mi)
#pragma unroll
            for (int g = 0; g < 2; ++g)
                ap[mi][g] = *(const s16x8*)&Pw[(mi * 16 + l16) * KSTR + g * 32 + quad * 8];
#pragma unroll
        for (int nt = 0; nt < 4; ++nt)
#pragma unroll
            for (int g = 0; g < 2; ++g)
                bv[nt][g] = *(const s16x8*)&Vs[p][(nt * 16 + l16) * KSTR + g * 32 + quad * 8];
        __builtin_amdgcn_s_setprio(1);
#pragma unroll
        for (int mi = 0; mi < 2; ++mi)
#pragma unroll
            for (int nt = 0; nt < 4; ++nt) {
                oacc[mi][nt] = MFMA(ap[mi][0], bv[nt][0], oacc[mi][nt]);
                oacc[mi][nt] = MFMA(ap[mi][1], bv[nt][1], oacc[mi][nt]);
            }
        __builtin_amdgcn_s_setprio(0);

        // write prefetched chunk into the alternate buffer (vmcnt wait lands here)
        if (it + 1 < NIT) {
#pragma unroll
            for (int i = 0; i < 2; ++i) {
                int r0 = sr + i * 32;
                *(s16x8*)&Ks[p ^ 1][r0 * KSTR + sg * 8] = kr[i];
                *(s16x8*)&Vs[p ^ 1][r0 * KSTR + sg * 8] = vr[i];
            }
        }
        __syncthreads();
    }

    // epilogue: reduce den across the 16 column-lanes, normalize, store bf16
#pragma unroll
    for (int mi = 0; mi < 2; ++mi)
#pragma unroll
        for (int r = 0; r < 4; ++r) {
            float d = dn[mi][r];
            d += __shfl_xor(d, 1);
            d += __shfl_xor(d, 2);
            d += __shfl_xor(d, 4);
            d += __shfl_xor(d, 8);
            float inv = 1.0f / d;
            int t = qrow0 + mi * 16 + quad * 4 + r;
#pragma unroll
            for (int nt = 0; nt < 4; ++nt)
                ao[(size_t)(b * Tn + t) * Wd + h * Dh + nt * 16 + l16] =
                    f2bf(oacc[mi][nt][r] * inv);
        }
}

#define LSTR 40   // proj LDS row stride (80 B = 5*16: b128-aligned, 2-way banks)

// ---------------------------------------------------------------------------
// Projection GEMM, double-buffered + async reg-staged prefetch, 1 barrier/iter:
// out[4096][1024] = A(bf16)[M][K] @ Wb(bf16)[N][K]^T + bias, fp32 out.
// Block 256 = 4 waves; tile 128m x 64n x 32k; wave = 64m x 32n (8 MFMA/chunk).
// ---------------------------------------------------------------------------
__global__ __launch_bounds__(256, 2) void proj_gemm(
    const short* __restrict__ A, const short* __restrict__ Wb,
    const float* __restrict__ bias, float* __restrict__ out)
{
    __shared__ alignas(16) short As[2][128 * LSTR];
    __shared__ alignas(16) short Bs[2][64 * LSTR];

    const int tid  = threadIdx.x;
    const int w    = tid >> 6;
    const int l    = tid & 63;
    const int quad = l >> 4;
    const int l16  = l & 15;

    const int bn = blockIdx.x & 15;    // 16 n-tiles
    const int bm = blockIdx.x >> 4;    // 32 m-tiles
    const int m0 = bm * 128;
    const int n0 = bn * 64;
    const int wm = (w & 1) * 64;       // wave m-offset
    const int wn = (w >> 1) * 32;      // wave n-offset

    const int rr = tid >> 2;   // staging row 0..63
    const int sg = tid & 3;    // 16B segment 0..3 (BK=32 shorts = 64B row)

    f32x4 acc[4][2];
#pragma unroll
    for (int mi = 0; mi < 4; ++mi)
#pragma unroll
        for (int nt = 0; nt < 2; ++nt) {
            acc[mi][nt][0] = 0.f; acc[mi][nt][1] = 0.f;
            acc[mi][nt][2] = 0.f; acc[mi][nt][3] = 0.f;
        }

    // prologue: stage k-chunk 0 into buffer 0
    s16x8 ra0 = ld8(A  + (size_t)(m0 + rr) * Wd + sg * 8);
    s16x8 ra1 = ld8(A  + (size_t)(m0 + 64 + rr) * Wd + sg * 8);
    s16x8 rb  = ld8(Wb + (size_t)(n0 + rr) * Wd + sg * 8);
    *(s16x8*)&As[0][rr * LSTR + sg * 8]        = ra0;
    *(s16x8*)&As[0][(rr + 64) * LSTR + sg * 8] = ra1;
    *(s16x8*)&Bs[0][rr * LSTR + sg * 8]        = rb;
    __syncthreads();

    for (int k0 = 0; k0 < Wd; k0 += 32) {
        const int p = (k0 >> 5) & 1;

        if (k0 + 32 < Wd) {
            ra0 = ld8(A  + (size_t)(m0 + rr) * Wd + k0 + 32 + sg * 8);
            ra1 = ld8(A  + (size_t)(m0 + 64 + rr) * Wd + k0 + 32 + sg * 8);
            rb  = ld8(Wb + (size_t)(n0 + rr) * Wd + k0 + 32 + sg * 8);
        }

        s16x8 a[4], bw[2];
#pragma unroll
        for (int mi = 0; mi < 4; ++mi)
            a[mi] = *(const s16x8*)&As[p][(wm + mi * 16 + l16) * LSTR + quad * 8];
#pragma unroll
        for (int nt = 0; nt < 2; ++nt)
            bw[nt] = *(const s16x8*)&Bs[p][(wn + nt * 16 + l16) * LSTR + quad * 8];
        __builtin_amdgcn_s_setprio(1);
#pragma unroll
        for (int mi = 0; mi < 4; ++mi)
#pragma unroll
            for (int nt = 0; nt < 2; ++nt)
                acc[mi][nt] = MFMA(a[mi], bw[nt], acc[mi][nt]);
        __builtin_amdgcn_s_setprio(0);

        if (k0 + 32 < Wd) {
            *(s16x8*)&As[p ^ 1][rr * LSTR + sg * 8]        = ra0;
            *(s16x8*)&As[p ^ 1][(rr + 64) * LSTR + sg * 8] = ra1;
            *(s16x8*)&Bs[p ^ 1][rr * LSTR + sg * 8]        = rb;
        }
        __syncthreads();
    }

#pragma unroll
    for (int nt = 0; nt < 2; ++nt) {
        float bv = bias[n0 + wn + nt * 16 + l16];
#pragma unroll
        for (int mi = 0; mi < 4; ++mi)
#pragma unroll
            for (int r = 0; r < 4; ++r)
                out[(size_t)(m0 + wm + mi * 16 + quad * 4 + r) * Wd + n0 + wn + nt * 16 + l16] =
                    acc[mi][nt][r] + bv;
    }
}

extern "C" void kernel_launch(void* const* d_in, const int* in_sizes, int n_in,
                              void* d_out, int out_size, void* d_ws, size_t ws_size,
                              hipStream_t stream) {
    const float* x  = (const float*)d_in[0];   // [2,2048,1024] fp32
    const float* ck = (const float*)d_in[1];   // [2,2048,1024] fp32
    const float* cv = (const float*)d_in[2];   // [2,2048,1024] fp32
    const float* wp = (const float*)d_in[3];   // [1024,1024]   fp32
    const float* bp = (const float*)d_in[4];   // [1024]        fp32

    const int nX = Bn * Tn * Wd;   // 4,194,304
    const int nW = Wd * Wd;        // 1,048,576

    short* kbb = (short*)d_ws;     // 8 MB  (K bf16)
    short* vtb = kbb + nX;         // 8 MB  (permuted V^T [bh][d][pos])
    short* wbb = vtb + nX;         // 2 MB  (Wp bf16)
    short* am  = wbb + nW;         // 8 MB  (attention output, bf16)

    cvt_scale<<<dim3(nX / 2048), dim3(256), 0, stream>>>(ck, kbb, nX, 1.0f);
    cvt_scale<<<dim3(nW / 2048), dim3(256), 0, stream>>>(wp, wbb, nW, 1.0f);
    vtrans<<<dim3(1024), dim3(256), 0, stream>>>(cv, vtb);

    attn_fused<<<dim3(Bn * Hn * (Tn / 128)), dim3(256), 0, stream>>>(x, kbb, vtb, am);
    proj_gemm<<<dim3((Bn * Tn / 128) * (Wd / 64)), dim3(256), 0, stream>>>(
        am, wbb, bp, (float*)d_out);
}

// Round 2
// 160.406 us; speedup vs baseline: 1.1162x; 1.0497x over previous
//
#include <hip/hip_runtime.h>

#define Bn 2
#define Hn 16
#define Tn 2048
#define Sn 2048
#define Wd 1024
#define Dh 64

typedef __attribute__((ext_vector_type(8))) short s16x8;
typedef __attribute__((ext_vector_type(4))) short s16x4;
typedef __attribute__((ext_vector_type(4))) float f32x4;
typedef __attribute__((ext_vector_type(4))) unsigned u32x4;

#define MFMA(a, b, c) __builtin_amdgcn_mfma_f32_16x16x32_bf16((a), (b), (c), 0, 0, 0)

__device__ __forceinline__ s16x8 ld8(const short* p) { return *(const s16x8*)p; }

// fp32 -> bf16 round-to-nearest-even
__device__ __forceinline__ short f2bf(float f) {
    unsigned u = __builtin_bit_cast(unsigned, f);
    u += 0x7FFFu + ((u >> 16) & 1u);
    return (short)(u >> 16);
}

// pack 2 f32 -> 2 bf16 (RNE) in one instruction
__device__ __forceinline__ unsigned cvtpk(float lo, float hi) {
    unsigned r;
    asm("v_cvt_pk_bf16_f32 %0, %1, %2" : "=v"(r) : "v"(lo), "v"(hi));
    return r;
}

// ---------------------------------------------------------------------------
// fp32 -> bf16 bulk convert with scale (8 elems/thread, coalesced)
// ---------------------------------------------------------------------------
__global__ void cvt_scale(const float* __restrict__ in, short* __restrict__ out,
                          int n, float s) {
    int i = (blockIdx.x * 256 + threadIdx.x) * 8;
    if (i < n) {
        float4 a = *(const float4*)(in + i);
        float4 b = *(const float4*)(in + i + 4);
        s16x8 o;
        o[0] = f2bf(a.x * s); o[1] = f2bf(a.y * s); o[2] = f2bf(a.z * s); o[3] = f2bf(a.w * s);
        o[4] = f2bf(b.x * s); o[5] = f2bf(b.y * s); o[6] = f2bf(b.z * s); o[7] = f2bf(b.w * s);
        *(s16x8*)(out + i) = o;
    }
}

// ---------------------------------------------------------------------------
// V -> V^T bf16 with s-position permutation matched to attn's in-register
// P fragments (swapped-QK layout):
//   position p (0..63) holds s = 16*(2*(p>>5) + ((p>>2)&1)) + ((p>>3)&3)*4 + (p&3)
// (dot products are k-order invariant as long as P-frags and V^T agree).
// vt[(b*16+h)*64+d][pos].  64x64 tiles via LDS.
// ---------------------------------------------------------------------------
__global__ __launch_bounds__(256) void vtrans(const float* __restrict__ cv,
                                              short* __restrict__ vt) {
    __shared__ short T[64][68];
    const int st = blockIdx.x & 31;          // s tile (64 wide)
    const int bh = blockIdx.x >> 5;          // 0..31
    const int b = bh >> 4, h = bh & 15;
    const int tid = threadIdx.x;
#pragma unroll
    for (int i = 0; i < 4; ++i) {
        int f = i * 256 + tid, sr = f >> 4, c4 = f & 15;
        float4 v = *(const float4*)(cv + (size_t)(b * Sn + st * 64 + sr) * Wd + h * Dh + c4 * 4);
        s16x4 o;
        o[0] = f2bf(v.x); o[1] = f2bf(v.y); o[2] = f2bf(v.z); o[3] = f2bf(v.w);
        *(s16x4*)&T[sr][c4 * 4] = o;
    }
    __syncthreads();
#pragma unroll
    for (int i = 0; i < 4; ++i) {
        int f = i * 256 + tid, dr = f >> 4, p4 = f & 15;
        s16x4 o;
#pragma unroll
        for (int k = 0; k < 4; ++k) {
            // p = p4*4 + k : s = 16*(2*(p4>>3) + (p4&1)) + ((p4>>1)&3)*4 + k
            int sl = ((p4 >> 3) * 2 + (p4 & 1)) * 16 + ((p4 >> 1) & 3) * 4 + k;
            o[k] = T[sl][dr];
        }
        *(s16x4*)(vt + (size_t)(bh * Dh + dr) * Sn + st * 64 + p4 * 4) = o;
    }
}

#define KSTR 72   // K/V LDS row stride in shorts (144 B = 9*16: b128-aligned,
                  // 4-bank row rotation -> uniform bank spread on b128 reads)

// ---------------------------------------------------------------------------
// Attention, swapped-QK^T -> P stays in registers (no LDS round-trip):
// sc = MFMA(K, Q) gives lane (quad,l16) scores[q=l16][s=sj*16+quad*4+r] --
// after exp2 + v_cvt_pk_bf16_f32 these ARE the PV A-frag k-slots for this
// lane (V^T position-permuted to match; see vtrans).  Per 64-S chunk:
// issue next chunk's global ld8s -> QK (16 MFMA) -> exp2/cvt_pk (in-reg) ->
// PV (16 MFMA) -> write prefetched regs to alternate LDS buffer -> 1 barrier.
// LDS traffic per wave-iter: 16 b128 reads + 4 b128 writes (was 24r+12w + fence).
// Grid 512, blk%8 = bh%8 -> XCD L2 locality.
// ---------------------------------------------------------------------------
__global__ __launch_bounds__(256, 2) void attn_fused(
    const float* __restrict__ x, const short* __restrict__ kb,
    const short* __restrict__ vt, short* __restrict__ ao)
{
    __shared__ alignas(16) short Ks[2][64 * KSTR];   // 18.4 KB
    __shared__ alignas(16) short Vs[2][64 * KSTR];   // 18.4 KB

    const int tid  = threadIdx.x;
    const int w    = tid >> 6;
    const int l    = tid & 63;
    const int quad = l >> 4;
    const int l16  = l & 15;

    const int bh = blockIdx.x & 31;          // blk%8 = bh%8 -> XCD locality
    const int qt = blockIdx.x >> 5;
    const int b  = bh >> 4, h = bh & 15;

    const int qrow0 = qt * 128 + w * 32;

    // Q B-frags from fp32, scaled by 0.125*log2e (folds 1/sqrt(d) and exp2 base)
    const float SQ = 0.125f * 1.4426950408889634f;
    s16x8 aq[2][2];
#pragma unroll
    for (int mi = 0; mi < 2; ++mi)
#pragma unroll
        for (int c = 0; c < 2; ++c) {
            const float* p = x + (size_t)(b * Tn + qrow0 + mi * 16 + l16) * Wd
                               + h * Dh + c * 32 + quad * 8;
            float4 a = ((const float4*)p)[0], bb = ((const float4*)p)[1];
            s16x8 o;
            o[0] = f2bf(a.x * SQ); o[1] = f2bf(a.y * SQ); o[2] = f2bf(a.z * SQ); o[3] = f2bf(a.w * SQ);
            o[4] = f2bf(bb.x * SQ); o[5] = f2bf(bb.y * SQ); o[6] = f2bf(bb.z * SQ); o[7] = f2bf(bb.w * SQ);
            aq[mi][c] = o;
        }

    f32x4 oacc[2][4];
    float dn[2];
#pragma unroll
    for (int mi = 0; mi < 2; ++mi) {
#pragma unroll
        for (int nt = 0; nt < 4; ++nt) {
            oacc[mi][nt][0] = 0.f; oacc[mi][nt][1] = 0.f;
            oacc[mi][nt][2] = 0.f; oacc[mi][nt][3] = 0.f;
        }
        dn[mi] = 0.f;
    }

    const short* kb_h = kb + (size_t)(b * Sn) * Wd + h * Dh;
    const short* vt_h = vt + (size_t)(bh * Dh) * Sn;

    const int sr = tid >> 3;   // staging row 0..31 (two passes: +0, +32)
    const int sg = tid & 7;    // 16B segment 0..7 within a 128B row

    // prologue: stage chunk 0 into buffer 0
    s16x8 kr[2], vr[2];
#pragma unroll
    for (int i = 0; i < 2; ++i) {
        int r0 = sr + i * 32;
        kr[i] = ld8(kb_h + (size_t)r0 * Wd + sg * 8);
        vr[i] = ld8(vt_h + (size_t)r0 * Sn + sg * 8);
    }
#pragma unroll
    for (int i = 0; i < 2; ++i) {
        int r0 = sr + i * 32;
        *(s16x8*)&Ks[0][r0 * KSTR + sg * 8] = kr[i];
        *(s16x8*)&Vs[0][r0 * KSTR + sg * 8] = vr[i];
    }
    __syncthreads();

    const int NIT = Sn / 64;
    for (int it = 0; it < NIT; ++it) {
        const int p = it & 1;

        // issue next chunk's global loads early (latency hides under compute)
        if (it + 1 < NIT) {
            const int s1 = (it + 1) * 64;
#pragma unroll
            for (int i = 0; i < 2; ++i) {
                int r0 = sr + i * 32;
                kr[i] = ld8(kb_h + (size_t)(s1 + r0) * Wd + sg * 8);
                vr[i] = ld8(vt_h + (size_t)r0 * Sn + s1 + sg * 8);
            }
        }

        // ---- QK (swapped): sc[mi][sj] = K-tile(sj) . Q(mi)^T ----
        // lane (quad,l16): sc[mi][sj][r] = scores[q=l16+mi*16][s=sj*16+quad*4+r]
        f32x4 sc[2][4];
        const f32x4 z = {0.f, 0.f, 0.f, 0.f};
        __builtin_amdgcn_s_setprio(1);
#pragma unroll
        for (int sj = 0; sj < 4; ++sj) {
            s16x8 k0 = *(const s16x8*)&Ks[p][(sj * 16 + l16) * KSTR + quad * 8];
            s16x8 k1 = *(const s16x8*)&Ks[p][(sj * 16 + l16) * KSTR + 32 + quad * 8];
#pragma unroll
            for (int mi = 0; mi < 2; ++mi) {
                sc[mi][sj] = MFMA(k0, aq[mi][0], z);
                sc[mi][sj] = MFMA(k1, aq[mi][1], sc[mi][sj]);
            }
        }
        __builtin_amdgcn_s_setprio(0);

        // ---- exp2 + pack to PV A-frags fully in-register ----
        // A-frag element j of ap[mi][g] must be P at s = 16*(2g+(j>>2)) + quad*4 + (j&3)
        //  = ex[sj=2g+(j>>2)][r=j&3]  -> dwords are cvt_pk of (r0,r1),(r2,r3).
        s16x8 ap[2][2];
#pragma unroll
        for (int mi = 0; mi < 2; ++mi) {
            float ex[4][4];
#pragma unroll
            for (int sj = 0; sj < 4; ++sj)
#pragma unroll
                for (int r = 0; r < 4; ++r)
                    ex[sj][r] = __builtin_amdgcn_exp2f(sc[mi][sj][r]);
            dn[mi] += (((ex[0][0] + ex[0][1]) + (ex[0][2] + ex[0][3]))
                     + ((ex[1][0] + ex[1][1]) + (ex[1][2] + ex[1][3])))
                    + (((ex[2][0] + ex[2][1]) + (ex[2][2] + ex[2][3]))
                     + ((ex[3][0] + ex[3][1]) + (ex[3][2] + ex[3][3])));
#pragma unroll
            for (int g = 0; g < 2; ++g) {
                u32x4 pk;
                pk[0] = cvtpk(ex[2 * g][0],     ex[2 * g][1]);
                pk[1] = cvtpk(ex[2 * g][2],     ex[2 * g][3]);
                pk[2] = cvtpk(ex[2 * g + 1][0], ex[2 * g + 1][1]);
                pk[3] = cvtpk(ex[2 * g + 1][2], ex[2 * g + 1][3]);
                ap[mi][g] = __builtin_bit_cast(s16x8, pk);
            }
        }

        // ---- PV: oacc[mi][nt] += P[mi] x V^T ----
        s16x8 bv[4][2];
#pragma unroll
        for (int nt = 0; nt < 4; ++nt)
#pragma unroll
            for (int g = 0; g < 2; ++g)
                bv[nt][g] = *(const s16x8*)&Vs[p][(nt * 16 + l16) * KSTR + g * 32 + quad * 8];
        __builtin_amdgcn_s_setprio(1);
#pragma unroll
        for (int mi = 0; mi < 2; ++mi)
#pragma unroll
            for (int nt = 0; nt < 4; ++nt) {
                oacc[mi][nt] = MFMA(ap[mi][0], bv[nt][0], oacc[mi][nt]);
                oacc[mi][nt] = MFMA(ap[mi][1], bv[nt][1], oacc[mi][nt]);
            }
        __builtin_amdgcn_s_setprio(0);

        // write prefetched chunk into the alternate buffer (vmcnt wait lands here)
        if (it + 1 < NIT) {
#pragma unroll
            for (int i = 0; i < 2; ++i) {
                int r0 = sr + i * 32;
                *(s16x8*)&Ks[p ^ 1][r0 * KSTR + sg * 8] = kr[i];
                *(s16x8*)&Vs[p ^ 1][r0 * KSTR + sg * 8] = vr[i];
            }
        }
        __syncthreads();
    }

    // epilogue: den reduce across the 4 quad-lanes (q = l16), broadcast per row,
    // normalize, store bf16
#pragma unroll
    for (int mi = 0; mi < 2; ++mi) {
        float d = dn[mi];
        d += __shfl_xor(d, 16);
        d += __shfl_xor(d, 32);
        float invl = 1.0f / d;          // lane l16 holds 1/den for q = l16
#pragma unroll
        for (int r = 0; r < 4; ++r) {
            float inv = __shfl(invl, quad * 4 + r);
            int t = qrow0 + mi * 16 + quad * 4 + r;
#pragma unroll
            for (int nt = 0; nt < 4; ++nt)
                ao[(size_t)(b * Tn + t) * Wd + h * Dh + nt * 16 + l16] =
                    f2bf(oacc[mi][nt][r] * inv);
        }
    }
}

#define LSTR 40   // proj LDS row stride (80 B = 5*16: b128-aligned, 2-way banks)

// ---------------------------------------------------------------------------
// Projection GEMM, double-buffered + async reg-staged prefetch, 1 barrier/iter:
// out[4096][1024] = A(bf16)[M][K] @ Wb(bf16)[N][K]^T + bias, fp32 out.
// Block 256 = 4 waves; tile 128m x 64n x 32k; wave = 64m x 32n (8 MFMA/chunk).
// ---------------------------------------------------------------------------
__global__ __launch_bounds__(256, 2) void proj_gemm(
    const short* __restrict__ A, const short* __restrict__ Wb,
    const float* __restrict__ bias, float* __restrict__ out)
{
    __shared__ alignas(16) short As[2][128 * LSTR];
    __shared__ alignas(16) short Bs[2][64 * LSTR];

    const int tid  = threadIdx.x;
    const int w    = tid >> 6;
    const int l    = tid & 63;
    const int quad = l >> 4;
    const int l16  = l & 15;

    const int bn = blockIdx.x & 15;    // 16 n-tiles
    const int bm = blockIdx.x >> 4;    // 32 m-tiles
    const int m0 = bm * 128;
    const int n0 = bn * 64;
    const int wm = (w & 1) * 64;       // wave m-offset
    const int wn = (w >> 1) * 32;      // wave n-offset

    const int rr = tid >> 2;   // staging row 0..63
    const int sg = tid & 3;    // 16B segment 0..3 (BK=32 shorts = 64B row)

    f32x4 acc[4][2];
#pragma unroll
    for (int mi = 0; mi < 4; ++mi)
#pragma unroll
        for (int nt = 0; nt < 2; ++nt) {
            acc[mi][nt][0] = 0.f; acc[mi][nt][1] = 0.f;
            acc[mi][nt][2] = 0.f; acc[mi][nt][3] = 0.f;
        }

    // prologue: stage k-chunk 0 into buffer 0
    s16x8 ra0 = ld8(A  + (size_t)(m0 + rr) * Wd + sg * 8);
    s16x8 ra1 = ld8(A  + (size_t)(m0 + 64 + rr) * Wd + sg * 8);
    s16x8 rb  = ld8(Wb + (size_t)(n0 + rr) * Wd + sg * 8);
    *(s16x8*)&As[0][rr * LSTR + sg * 8]        = ra0;
    *(s16x8*)&As[0][(rr + 64) * LSTR + sg * 8] = ra1;
    *(s16x8*)&Bs[0][rr * LSTR + sg * 8]        = rb;
    __syncthreads();

    for (int k0 = 0; k0 < Wd; k0 += 32) {
        const int p = (k0 >> 5) & 1;

        if (k0 + 32 < Wd) {
            ra0 = ld8(A  + (size_t)(m0 + rr) * Wd + k0 + 32 + sg * 8);
            ra1 = ld8(A  + (size_t)(m0 + 64 + rr) * Wd + k0 + 32 + sg * 8);
            rb  = ld8(Wb + (size_t)(n0 + rr) * Wd + k0 + 32 + sg * 8);
        }

        s16x8 a[4], bw[2];
#pragma unroll
        for (int mi = 0; mi < 4; ++mi)
            a[mi] = *(const s16x8*)&As[p][(wm + mi * 16 + l16) * LSTR + quad * 8];
#pragma unroll
        for (int nt = 0; nt < 2; ++nt)
            bw[nt] = *(const s16x8*)&Bs[p][(wn + nt * 16 + l16) * LSTR + quad * 8];
        __builtin_amdgcn_s_setprio(1);
#pragma unroll
        for (int mi = 0; mi < 4; ++mi)
#pragma unroll
            for (int nt = 0; nt < 2; ++nt)
                acc[mi][nt] = MFMA(a[mi], bw[nt], acc[mi][nt]);
        __builtin_amdgcn_s_setprio(0);

        if (k0 + 32 < Wd) {
            *(s16x8*)&As[p ^ 1][rr * LSTR + sg * 8]        = ra0;
            *(s16x8*)&As[p ^ 1][(rr + 64) * LSTR + sg * 8] = ra1;
            *(s16x8*)&Bs[p ^ 1][rr * LSTR + sg * 8]        = rb;
        }
        __syncthreads();
    }

#pragma unroll
    for (int nt = 0; nt < 2; ++nt) {
        float bv = bias[n0 + wn + nt * 16 + l16];
#pragma unroll
        for (int mi = 0; mi < 4; ++mi)
#pragma unroll
            for (int r = 0; r < 4; ++r)
                out[(size_t)(m0 + wm + mi * 16 + quad * 4 + r) * Wd + n0 + wn + nt * 16 + l16] =
                    acc[mi][nt][r] + bv;
    }
}

extern "C" void kernel_launch(void* const* d_in, const int* in_sizes, int n_in,
                              void* d_out, int out_size, void* d_ws, size_t ws_size,
                              hipStream_t stream) {
    const float* x  = (const float*)d_in[0];   // [2,2048,1024] fp32
    const float* ck = (const float*)d_in[1];   // [2,2048,1024] fp32
    const float* cv = (const float*)d_in[2];   // [2,2048,1024] fp32
    const float* wp = (const float*)d_in[3];   // [1024,1024]   fp32
    const float* bp = (const float*)d_in[4];   // [1024]        fp32

    const int nX = Bn * Tn * Wd;   // 4,194,304
    const int nW = Wd * Wd;        // 1,048,576

    short* kbb = (short*)d_ws;     // 8 MB  (K bf16)
    short* vtb = kbb + nX;         // 8 MB  (permuted V^T [bh][d][pos])
    short* wbb = vtb + nX;         // 2 MB  (Wp bf16)
    short* am  = wbb + nW;         // 8 MB  (attention output, bf16)

    cvt_scale<<<dim3(nX / 2048), dim3(256), 0, stream>>>(ck, kbb, nX, 1.0f);
    cvt_scale<<<dim3(nW / 2048), dim3(256), 0, stream>>>(wp, wbb, nW, 1.0f);
    vtrans<<<dim3(1024), dim3(256), 0, stream>>>(cv, vtb);

    attn_fused<<<dim3(Bn * Hn * (Tn / 128)), dim3(256), 0, stream>>>(x, kbb, vtb, am);
    proj_gemm<<<dim3((Bn * Tn / 128) * (Wd / 64)), dim3(256), 0, stream>>>(
        am, wbb, bp, (float*)d_out);
}

// Round 3
// 155.860 us; speedup vs baseline: 1.1487x; 1.0292x over previous
//
#include <hip/hip_runtime.h>

#define Bn 2
#define Hn 16
#define Tn 2048
#define Sn 2048
#define Wd 1024
#define Dh 64

typedef __attribute__((ext_vector_type(8))) short s16x8;
typedef __attribute__((ext_vector_type(4))) short s16x4;
typedef __attribute__((ext_vector_type(4))) float f32x4;
typedef __attribute__((ext_vector_type(4))) unsigned u32x4;

#define MFMA(a, b, c) __builtin_amdgcn_mfma_f32_16x16x32_bf16((a), (b), (c), 0, 0, 0)

__device__ __forceinline__ s16x8 ld8(const short* p) { return *(const s16x8*)p; }

// fp32 -> bf16 round-to-nearest-even
__device__ __forceinline__ short f2bf(float f) {
    unsigned u = __builtin_bit_cast(unsigned, f);
    u += 0x7FFFu + ((u >> 16) & 1u);
    return (short)(u >> 16);
}

// pack 2 f32 -> 2 bf16 (RNE) in one instruction
__device__ __forceinline__ unsigned cvtpk(float lo, float hi) {
    unsigned r;
    asm("v_cvt_pk_bf16_f32 %0, %1, %2" : "=v"(r) : "v"(lo), "v"(hi));
    return r;
}

// ---------------------------------------------------------------------------
// prep: single launch doing all preprocessing.
//   blk <  1024 : K-pack  -> kp, MFMA A-frag order:
//                 group (bh, t16 = s/16, g): 64 lanes x 16B; lane l=(quad,l16),
//                 elem j = K[b][t16*16+l16][h*64 + g*32 + quad*8 + j]  (bf16)
//   blk <  2048 : V-pack  -> vp, MFMA B-frag order with s-permutation matched
//                 to attn's in-register P frags:
//                 group (bh, sc = s/64, nt, g): lane l, elem j =
//                 V[b][sc*64 + 16*(2g+(j>>2)) + quad*4 + (j&3)][h*64+nt*16+l16]
//   blk >= 2048 : w_proj fp32 -> bf16 bulk convert
// Fragment reads in attn become single fully-coalesced 1KB global loads.
// ---------------------------------------------------------------------------
__global__ __launch_bounds__(256) void prep(const float* __restrict__ ck,
                                            const float* __restrict__ cv,
                                            const float* __restrict__ wp,
                                            short* __restrict__ kp,
                                            short* __restrict__ vp,
                                            short* __restrict__ wb)
{
    __shared__ short T[64][72];   // 64x64 bf16 tile, stride 144B (9*16: b128-aligned)
    const int blk = blockIdx.x;
    const int tid = threadIdx.x;
    if (blk < 2048) {
        const int isV = blk >> 10;           // 0 = kpack, 1 = vpack
        const int c   = blk & 1023;
        const int bh = c >> 5, sc = c & 31;
        const int b = bh >> 4, h = bh & 15;
        const float* src = (isV ? cv : ck) + (size_t)(b * Sn + sc * 64) * Wd + h * Dh;
#pragma unroll
        for (int i = 0; i < 4; ++i) {
            int f = i * 256 + tid, sr = f >> 4, c4 = f & 15;
            float4 v = *(const float4*)(src + (size_t)sr * Wd + c4 * 4);
            s16x4 o;
            o[0] = f2bf(v.x); o[1] = f2bf(v.y); o[2] = f2bf(v.z); o[3] = f2bf(v.w);
            *(s16x4*)&T[sr][c4 * 4] = o;
        }
        __syncthreads();
        const int rt = tid >> 6;             // t16-local (K) or nt (V), 0..3
        const int l = tid & 63, quad = l >> 4, l16 = l & 15;
        if (!isV) {
            size_t base = ((size_t)((bh * 128 + sc * 4 + rt) * 2)) * 512 + l * 8;
            *(s16x8*)(kp + base)       = *(const s16x8*)&T[rt * 16 + l16][quad * 8];
            *(s16x8*)(kp + base + 512) = *(const s16x8*)&T[rt * 16 + l16][32 + quad * 8];
        } else {
#pragma unroll
            for (int g = 0; g < 2; ++g) {
                s16x8 o;
#pragma unroll
                for (int j = 0; j < 8; ++j) {
                    int s = 32 * g + 16 * (j >> 2) + quad * 4 + (j & 3);
                    o[j] = T[s][rt * 16 + l16];
                }
                *(s16x8*)(vp + ((size_t)((bh * 32 + sc) * 8 + rt * 2 + g)) * 512 + l * 8) = o;
            }
        }
    } else {
        int i = ((blk - 2048) * 256 + tid) * 8;
        float4 a = *(const float4*)(wp + i);
        float4 b = *(const float4*)(wp + i + 4);
        s16x8 o;
        o[0] = f2bf(a.x); o[1] = f2bf(a.y); o[2] = f2bf(a.z); o[3] = f2bf(a.w);
        o[4] = f2bf(b.x); o[5] = f2bf(b.y); o[6] = f2bf(b.z); o[7] = f2bf(b.w);
        *(s16x8*)(wb + i) = o;
    }
}

// ---------------------------------------------------------------------------
// Attention, LDS-free: K/V streamed as pre-packed MFMA fragments from L1/L2
// (512 KB per (b,h), L2-resident; same-bh blocks pinned to one XCD by the
// blk%8 = bh%8 swizzle; the 8 waves on a CU share one bh stream -> L1 reuse).
// No barriers, no LDS: pure per-wave dataflow. Per 64-S chunk:
//   prefetch next chunk's 8 K-frag loads (double-buffered regs) ->
//   issue this chunk's 8 V-frag loads -> QK (16 MFMA, swapped: P in regs) ->
//   exp2 + v_cvt_pk_bf16_f32 -> denominator via ones-column MFMA (4) ->
//   PV (16 MFMA).
// Denominator lands in row q = quad*4+r of dnacc -- exactly the epilogue
// layout, zero shuffles.
// ---------------------------------------------------------------------------
__global__ __launch_bounds__(256, 2) void attn_fused(
    const float* __restrict__ x, const short* __restrict__ kp,
    const short* __restrict__ vt, short* __restrict__ ao)
{
    const int tid  = threadIdx.x;
    const int w    = tid >> 6;
    const int l    = tid & 63;
    const int quad = l >> 4;
    const int l16  = l & 15;

    const int bh = blockIdx.x & 31;          // blk%8 = bh%8 -> XCD locality
    const int qt = blockIdx.x >> 5;
    const int b  = bh >> 4, h = bh & 15;

    const int qrow0 = qt * 128 + w * 32;

    // Q B-frags from fp32, scaled by 0.125*log2e (folds 1/sqrt(d) and exp2 base)
    const float SQ = 0.125f * 1.4426950408889634f;
    s16x8 aq[2][2];
#pragma unroll
    for (int mi = 0; mi < 2; ++mi)
#pragma unroll
        for (int c = 0; c < 2; ++c) {
            const float* p = x + (size_t)(b * Tn + qrow0 + mi * 16 + l16) * Wd
                               + h * Dh + c * 32 + quad * 8;
            float4 a = ((const float4*)p)[0], bb = ((const float4*)p)[1];
            s16x8 o;
            o[0] = f2bf(a.x * SQ); o[1] = f2bf(a.y * SQ); o[2] = f2bf(a.z * SQ); o[3] = f2bf(a.w * SQ);
            o[4] = f2bf(bb.x * SQ); o[5] = f2bf(bb.y * SQ); o[6] = f2bf(bb.z * SQ); o[7] = f2bf(bb.w * SQ);
            aq[mi][c] = o;
        }

    f32x4 oacc[2][4], dnacc[2];
#pragma unroll
    for (int mi = 0; mi < 2; ++mi) {
#pragma unroll
        for (int nt = 0; nt < 4; ++nt) {
            oacc[mi][nt][0] = 0.f; oacc[mi][nt][1] = 0.f;
            oacc[mi][nt][2] = 0.f; oacc[mi][nt][3] = 0.f;
        }
        dnacc[mi][0] = 0.f; dnacc[mi][1] = 0.f; dnacc[mi][2] = 0.f; dnacc[mi][3] = 0.f;
    }

    s16x8 ones;
#pragma unroll
    for (int j = 0; j < 8; ++j) ones[j] = (short)0x3F80;   // bf16 1.0

    const short* kp_h = kp + (size_t)bh * 131072;   // 128 t16 x 2 g x 512 shorts
    const short* vp_h = vt + (size_t)bh * 131072;   // 32 sc x 8 (nt,g) x 512 shorts

    const f32x4 z = {0.f, 0.f, 0.f, 0.f};
    const int NIT = Sn / 64;

    s16x8 kfA[4][2], kfB[4][2];
#pragma unroll
    for (int sj = 0; sj < 4; ++sj)
#pragma unroll
        for (int g = 0; g < 2; ++g)
            kfA[sj][g] = ld8(kp_h + ((size_t)(sj * 2 + g)) * 512 + l * 8);

#define BODY(KF, KN, itv)                                                       \
    do {                                                                        \
        if ((itv) + 1 < NIT) {                                                  \
            _Pragma("unroll") for (int sj = 0; sj < 4; ++sj)                    \
                _Pragma("unroll") for (int g = 0; g < 2; ++g)                   \
                    KN[sj][g] = ld8(kp_h +                                      \
                        ((size_t)(((itv) + 1) * 8 + sj * 2 + g)) * 512 + l * 8);\
        }                                                                       \
        s16x8 vf[4][2];                                                         \
        _Pragma("unroll") for (int nt = 0; nt < 4; ++nt)                        \
            _Pragma("unroll") for (int g = 0; g < 2; ++g)                       \
                vf[nt][g] = ld8(vp_h +                                          \
                    ((size_t)((itv) * 8 + nt * 2 + g)) * 512 + l * 8);          \
        f32x4 sc[2][4];                                                         \
        __builtin_amdgcn_s_setprio(1);                                          \
        _Pragma("unroll") for (int sj = 0; sj < 4; ++sj)                        \
            _Pragma("unroll") for (int mi = 0; mi < 2; ++mi) {                  \
                sc[mi][sj] = MFMA(KF[sj][0], aq[mi][0], z);                     \
                sc[mi][sj] = MFMA(KF[sj][1], aq[mi][1], sc[mi][sj]);            \
            }                                                                   \
        __builtin_amdgcn_s_setprio(0);                                          \
        s16x8 ap[2][2];                                                         \
        _Pragma("unroll") for (int mi = 0; mi < 2; ++mi) {                      \
            float ex[4][4];                                                     \
            _Pragma("unroll") for (int sj = 0; sj < 4; ++sj)                    \
                _Pragma("unroll") for (int r = 0; r < 4; ++r)                   \
                    ex[sj][r] = __builtin_amdgcn_exp2f(sc[mi][sj][r]);          \
            _Pragma("unroll") for (int g = 0; g < 2; ++g) {                     \
                u32x4 pk;                                                       \
                pk[0] = cvtpk(ex[2 * g][0],     ex[2 * g][1]);                  \
                pk[1] = cvtpk(ex[2 * g][2],     ex[2 * g][3]);                  \
                pk[2] = cvtpk(ex[2 * g + 1][0], ex[2 * g + 1][1]);              \
                pk[3] = cvtpk(ex[2 * g + 1][2], ex[2 * g + 1][3]);              \
                ap[mi][g] = __builtin_bit_cast(s16x8, pk);                      \
            }                                                                   \
        }                                                                       \
        __builtin_amdgcn_s_setprio(1);                                          \
        _Pragma("unroll") for (int mi = 0; mi < 2; ++mi) {                      \
            dnacc[mi] = MFMA(ap[mi][0], ones, dnacc[mi]);                       \
            dnacc[mi] = MFMA(ap[mi][1], ones, dnacc[mi]);                       \
        }                                                                       \
        _Pragma("unroll") for (int mi = 0; mi < 2; ++mi)                        \
            _Pragma("unroll") for (int nt = 0; nt < 4; ++nt) {                  \
                oacc[mi][nt] = MFMA(ap[mi][0], vf[nt][0], oacc[mi][nt]);        \
                oacc[mi][nt] = MFMA(ap[mi][1], vf[nt][1], oacc[mi][nt]);        \
            }                                                                   \
        __builtin_amdgcn_s_setprio(0);                                          \
    } while (0)

    for (int it = 0; it < NIT; it += 2) {
        BODY(kfA, kfB, it);
        BODY(kfB, kfA, it + 1);
    }
#undef BODY

    // epilogue: dnacc row q=quad*4+r already holds the denominator for that q
#pragma unroll
    for (int mi = 0; mi < 2; ++mi)
#pragma unroll
        for (int r = 0; r < 4; ++r) {
            float inv = 1.0f / dnacc[mi][r];
            int t = qrow0 + mi * 16 + quad * 4 + r;
#pragma unroll
            for (int nt = 0; nt < 4; ++nt)
                ao[(size_t)(b * Tn + t) * Wd + h * Dh + nt * 16 + l16] =
                    f2bf(oacc[mi][nt][r] * inv);
        }
}

#define LSTR 40   // proj LDS row stride (80 B = 5*16: b128-aligned, 2-way banks)

// ---------------------------------------------------------------------------
// Projection GEMM, double-buffered + async reg-staged prefetch, 1 barrier/iter:
// out[4096][1024] = A(bf16)[M][K] @ Wb(bf16)[N][K]^T + bias, fp32 out.
// Block 256 = 4 waves; tile 128m x 64n x 32k; wave = 64m x 32n (8 MFMA/chunk).
// ---------------------------------------------------------------------------
__global__ __launch_bounds__(256, 2) void proj_gemm(
    const short* __restrict__ A, const short* __restrict__ Wb,
    const float* __restrict__ bias, float* __restrict__ out)
{
    __shared__ alignas(16) short As[2][128 * LSTR];
    __shared__ alignas(16) short Bs[2][64 * LSTR];

    const int tid  = threadIdx.x;
    const int w    = tid >> 6;
    const int l    = tid & 63;
    const int quad = l >> 4;
    const int l16  = l & 15;

    const int bn = blockIdx.x & 15;    // 16 n-tiles
    const int bm = blockIdx.x >> 4;    // 32 m-tiles
    const int m0 = bm * 128;
    const int n0 = bn * 64;
    const int wm = (w & 1) * 64;       // wave m-offset
    const int wn = (w >> 1) * 32;      // wave n-offset

    const int rr = tid >> 2;   // staging row 0..63
    const int sg = tid & 3;    // 16B segment 0..3 (BK=32 shorts = 64B row)

    f32x4 acc[4][2];
#pragma unroll
    for (int mi = 0; mi < 4; ++mi)
#pragma unroll
        for (int nt = 0; nt < 2; ++nt) {
            acc[mi][nt][0] = 0.f; acc[mi][nt][1] = 0.f;
            acc[mi][nt][2] = 0.f; acc[mi][nt][3] = 0.f;
        }

    // prologue: stage k-chunk 0 into buffer 0
    s16x8 ra0 = ld8(A  + (size_t)(m0 + rr) * Wd + sg * 8);
    s16x8 ra1 = ld8(A  + (size_t)(m0 + 64 + rr) * Wd + sg * 8);
    s16x8 rb  = ld8(Wb + (size_t)(n0 + rr) * Wd + sg * 8);
    *(s16x8*)&As[0][rr * LSTR + sg * 8]        = ra0;
    *(s16x8*)&As[0][(rr + 64) * LSTR + sg * 8] = ra1;
    *(s16x8*)&Bs[0][rr * LSTR + sg * 8]        = rb;
    __syncthreads();

    for (int k0 = 0; k0 < Wd; k0 += 32) {
        const int p = (k0 >> 5) & 1;

        if (k0 + 32 < Wd) {
            ra0 = ld8(A  + (size_t)(m0 + rr) * Wd + k0 + 32 + sg * 8);
            ra1 = ld8(A  + (size_t)(m0 + 64 + rr) * Wd + k0 + 32 + sg * 8);
            rb  = ld8(Wb + (size_t)(n0 + rr) * Wd + k0 + 32 + sg * 8);
        }

        s16x8 a[4], bw[2];
#pragma unroll
        for (int mi = 0; mi < 4; ++mi)
            a[mi] = *(const s16x8*)&As[p][(wm + mi * 16 + l16) * LSTR + quad * 8];
#pragma unroll
        for (int nt = 0; nt < 2; ++nt)
            bw[nt] = *(const s16x8*)&Bs[p][(wn + nt * 16 + l16) * LSTR + quad * 8];
        __builtin_amdgcn_s_setprio(1);
#pragma unroll
        for (int mi = 0; mi < 4; ++mi)
#pragma unroll
            for (int nt = 0; nt < 2; ++nt)
                acc[mi][nt] = MFMA(a[mi], bw[nt], acc[mi][nt]);
        __builtin_amdgcn_s_setprio(0);

        if (k0 + 32 < Wd) {
            *(s16x8*)&As[p ^ 1][rr * LSTR + sg * 8]        = ra0;
            *(s16x8*)&As[p ^ 1][(rr + 64) * LSTR + sg * 8] = ra1;
            *(s16x8*)&Bs[p ^ 1][rr * LSTR + sg * 8]        = rb;
        }
        __syncthreads();
    }

#pragma unroll
    for (int nt = 0; nt < 2; ++nt) {
        float bv = bias[n0 + wn + nt * 16 + l16];
#pragma unroll
        for (int mi = 0; mi < 4; ++mi)
#pragma unroll
            for (int r = 0; r < 4; ++r)
                out[(size_t)(m0 + wm + mi * 16 + quad * 4 + r) * Wd + n0 + wn + nt * 16 + l16] =
                    acc[mi][nt][r] + bv;
    }
}

extern "C" void kernel_launch(void* const* d_in, const int* in_sizes, int n_in,
                              void* d_out, int out_size, void* d_ws, size_t ws_size,
                              hipStream_t stream) {
    const float* x  = (const float*)d_in[0];   // [2,2048,1024] fp32
    const float* ck = (const float*)d_in[1];   // [2,2048,1024] fp32
    const float* cv = (const float*)d_in[2];   // [2,2048,1024] fp32
    const float* wp = (const float*)d_in[3];   // [1024,1024]   fp32
    const float* bp = (const float*)d_in[4];   // [1024]        fp32

    const int nX = Bn * Tn * Wd;   // 4,194,304
    const int nW = Wd * Wd;        // 1,048,576

    short* kpb = (short*)d_ws;     // 8 MB  (K, MFMA A-frag packed)
    short* vpb = kpb + nX;         // 8 MB  (V^T, MFMA B-frag packed + s-perm)
    short* wbb = vpb + nX;         // 2 MB  (Wp bf16)
    short* am  = wbb + nW;         // 8 MB  (attention output, bf16)

    prep<<<dim3(2048 + nW / 2048), dim3(256), 0, stream>>>(ck, cv, wp, kpb, vpb, wbb);

    attn_fused<<<dim3(Bn * Hn * (Tn / 128)), dim3(256), 0, stream>>>(x, kpb, vpb, am);
    proj_gemm<<<dim3((Bn * Tn / 128) * (Wd / 64)), dim3(256), 0, stream>>>(
        am, wbb, bp, (float*)d_out);
}

// Round 4
// 152.972 us; speedup vs baseline: 1.1704x; 1.0189x over previous
//
#include <hip/hip_runtime.h>

#define Bn 2
#define Hn 16
#define Tn 2048
#define Sn 2048
#define Wd 1024
#define Dh 64

typedef __attribute__((ext_vector_type(8))) short s16x8;
typedef __attribute__((ext_vector_type(4))) short s16x4;
typedef __attribute__((ext_vector_type(4))) float f32x4;
typedef __attribute__((ext_vector_type(4))) unsigned u32x4;

#define MFMA(a, b, c) __builtin_amdgcn_mfma_f32_16x16x32_bf16((a), (b), (c), 0, 0, 0)

__device__ __forceinline__ s16x8 ld8(const short* p) { return *(const s16x8*)p; }

// fp32 -> bf16 round-to-nearest-even
__device__ __forceinline__ short f2bf(float f) {
    unsigned u = __builtin_bit_cast(unsigned, f);
    u += 0x7FFFu + ((u >> 16) & 1u);
    return (short)(u >> 16);
}

// pack 2 f32 -> 2 bf16 (RNE) in one instruction
__device__ __forceinline__ unsigned cvtpk(float lo, float hi) {
    unsigned r;
    asm("v_cvt_pk_bf16_f32 %0, %1, %2" : "=v"(r) : "v"(lo), "v"(hi));
    return r;
}

// async global->LDS, 16B/lane: LDS dest = wave-uniform base + lane*16
__device__ __forceinline__ void gl_lds(const short* g, short* lds) {
    __builtin_amdgcn_global_load_lds(
        (const __attribute__((address_space(1))) void*)g,
        (__attribute__((address_space(3))) void*)lds, 16, 0, 0);
}

// ---------------------------------------------------------------------------
// prep: single launch doing all preprocessing.
//   blk <  1024 : K-pack  -> kp, MFMA A-frag order:
//                 group (bh, t16 = s/16, g): 64 lanes x 16B; lane l=(quad,l16),
//                 elem j = K[b][t16*16+l16][h*64 + g*32 + quad*8 + j]  (bf16)
//   blk <  2048 : V-pack  -> vp, MFMA B-frag order with s-permutation matched
//                 to attn's in-register P frags:
//                 group (bh, sc = s/64, nt, g): lane l, elem j =
//                 V[b][sc*64 + 16*(2g+(j>>2)) + quad*4 + (j&3)][h*64+nt*16+l16]
//   blk >= 2048 : w_proj fp32 -> bf16 bulk convert
// Fragment groups are contiguous 1KB: attn stages them with global_load_lds
// (linear lane*16 scatter) and reads them as conflict-free ds_read_b128.
// ---------------------------------------------------------------------------
__global__ __launch_bounds__(256) void prep(const float* __restrict__ ck,
                                            const float* __restrict__ cv,
                                            const float* __restrict__ wp,
                                            short* __restrict__ kp,
                                            short* __restrict__ vp,
                                            short* __restrict__ wb)
{
    __shared__ short T[64][72];   // 64x64 bf16 tile, stride 144B (9*16: b128-aligned)
    const int blk = blockIdx.x;
    const int tid = threadIdx.x;
    if (blk < 2048) {
        const int isV = blk >> 10;           // 0 = kpack, 1 = vpack
        const int c   = blk & 1023;
        const int bh = c >> 5, sc = c & 31;
        const int b = bh >> 4, h = bh & 15;
        const float* src = (isV ? cv : ck) + (size_t)(b * Sn + sc * 64) * Wd + h * Dh;
#pragma unroll
        for (int i = 0; i < 4; ++i) {
            int f = i * 256 + tid, sr = f >> 4, c4 = f & 15;
            float4 v = *(const float4*)(src + (size_t)sr * Wd + c4 * 4);
            s16x4 o;
            o[0] = f2bf(v.x); o[1] = f2bf(v.y); o[2] = f2bf(v.z); o[3] = f2bf(v.w);
            *(s16x4*)&T[sr][c4 * 4] = o;
        }
        __syncthreads();
        const int rt = tid >> 6;             // t16-local (K) or nt (V), 0..3
        const int l = tid & 63, quad = l >> 4, l16 = l & 15;
        if (!isV) {
            size_t base = ((size_t)((bh * 128 + sc * 4 + rt) * 2)) * 512 + l * 8;
            *(s16x8*)(kp + base)       = *(const s16x8*)&T[rt * 16 + l16][quad * 8];
            *(s16x8*)(kp + base + 512) = *(const s16x8*)&T[rt * 16 + l16][32 + quad * 8];
        } else {
#pragma unroll
            for (int g = 0; g < 2; ++g) {
                s16x8 o;
#pragma unroll
                for (int j = 0; j < 8; ++j) {
                    int s = 32 * g + 16 * (j >> 2) + quad * 4 + (j & 3);
                    o[j] = T[s][rt * 16 + l16];
                }
                *(s16x8*)(vp + ((size_t)((bh * 32 + sc) * 8 + rt * 2 + g)) * 512 + l * 8) = o;
            }
        }
    } else {
        int i = ((blk - 2048) * 256 + tid) * 8;
        float4 a = *(const float4*)(wp + i);
        float4 b = *(const float4*)(wp + i + 4);
        s16x8 o;
        o[0] = f2bf(a.x); o[1] = f2bf(a.y); o[2] = f2bf(a.z); o[3] = f2bf(a.w);
        o[4] = f2bf(b.x); o[5] = f2bf(b.y); o[6] = f2bf(b.z); o[7] = f2bf(b.w);
        *(s16x8*)(wb + i) = o;
    }
}

// ---------------------------------------------------------------------------
// Attention: packed-fragment K/V staged cooperatively into LDS via
// global_load_lds (16B/lane, linear 1KB groups), double-buffered, ONE
// vmcnt(0)+barrier per 64-S chunk.  Block traffic = 512KB per block (shared
// by 4 waves) instead of per wave (R3 streamed 4MB/CU; now 1MB/CU).
// Fragments read back as contiguous ds_read_b128 (conflict-free, ~12cy).
// Per chunk: stage(t+1) -> QK (16 MFMA, swapped: P in regs) -> exp2 +
// cvt_pk -> denominator ones-MFMA (4) -> PV (16 MFMA) -> vmcnt(0), barrier.
// Grid 512, blk%8 = bh%8 -> XCD L2 locality.
// ---------------------------------------------------------------------------
__global__ __launch_bounds__(256, 2) void attn_fused(
    const float* __restrict__ x, const short* __restrict__ kp,
    const short* __restrict__ vt, short* __restrict__ ao)
{
    __shared__ alignas(16) short Ks[2][8 * 512];   // 8KB per buffer
    __shared__ alignas(16) short Vs[2][8 * 512];   // 8KB per buffer

    const int tid  = threadIdx.x;
    const int w    = tid >> 6;
    const int l    = tid & 63;
    const int quad = l >> 4;
    const int l16  = l & 15;

    const int bh = blockIdx.x & 31;          // blk%8 = bh%8 -> XCD locality
    const int qt = blockIdx.x >> 5;
    const int b  = bh >> 4, h = bh & 15;

    const int qrow0 = qt * 128 + w * 32;

    const short* kp_h = kp + (size_t)bh * 131072;   // 128 t16 x 2 g x 512 shorts
    const short* vp_h = vt + (size_t)bh * 131072;   // 32 sc x 8 (nt,g) x 512 shorts

    // wave w stages fragment groups {2w, 2w+1} of K and V each chunk
    const int f0 = w * 2;

    // prologue: stage chunk 0 into buffer 0 (issued before Q loads so the
    // VMEM queue overlaps the Q fp32 reads)
#pragma unroll
    for (int f2 = 0; f2 < 2; ++f2) {
        int f = f0 + f2;
        gl_lds(kp_h + (size_t)f * 512 + l * 8, &Ks[0][f * 512]);
        gl_lds(vp_h + (size_t)f * 512 + l * 8, &Vs[0][f * 512]);
    }

    // Q B-frags from fp32, scaled by 0.125*log2e (folds 1/sqrt(d) and exp2 base)
    const float SQ = 0.125f * 1.4426950408889634f;
    s16x8 aq[2][2];
#pragma unroll
    for (int mi = 0; mi < 2; ++mi)
#pragma unroll
        for (int c = 0; c < 2; ++c) {
            const float* p = x + (size_t)(b * Tn + qrow0 + mi * 16 + l16) * Wd
                               + h * Dh + c * 32 + quad * 8;
            float4 a = ((const float4*)p)[0], bb = ((const float4*)p)[1];
            s16x8 o;
            o[0] = f2bf(a.x * SQ); o[1] = f2bf(a.y * SQ); o[2] = f2bf(a.z * SQ); o[3] = f2bf(a.w * SQ);
            o[4] = f2bf(bb.x * SQ); o[5] = f2bf(bb.y * SQ); o[6] = f2bf(bb.z * SQ); o[7] = f2bf(bb.w * SQ);
            aq[mi][c] = o;
        }

    f32x4 oacc[2][4], dnacc[2];
#pragma unroll
    for (int mi = 0; mi < 2; ++mi) {
#pragma unroll
        for (int nt = 0; nt < 4; ++nt) {
            oacc[mi][nt][0] = 0.f; oacc[mi][nt][1] = 0.f;
            oacc[mi][nt][2] = 0.f; oacc[mi][nt][3] = 0.f;
        }
        dnacc[mi][0] = 0.f; dnacc[mi][1] = 0.f; dnacc[mi][2] = 0.f; dnacc[mi][3] = 0.f;
    }

    s16x8 ones;
#pragma unroll
    for (int j = 0; j < 8; ++j) ones[j] = (short)0x3F80;   // bf16 1.0

    const f32x4 z = {0.f, 0.f, 0.f, 0.f};
    const int NIT = Sn / 64;

    // chunk-0 staging (and Q loads) must be complete before first reads
    asm volatile("s_waitcnt vmcnt(0)" ::: "memory");
    __syncthreads();

    for (int it = 0; it < NIT; ++it) {
        const int p = it & 1;

        // issue next chunk's staging into the alternate buffer
        if (it + 1 < NIT) {
            const size_t cbase = (size_t)(it + 1) * 8;
#pragma unroll
            for (int f2 = 0; f2 < 2; ++f2) {
                int f = f0 + f2;
                gl_lds(kp_h + (cbase + f) * 512 + l * 8, &Ks[p ^ 1][f * 512]);
                gl_lds(vp_h + (cbase + f) * 512 + l * 8, &Vs[p ^ 1][f * 512]);
            }
        }

        // ---- fragment reads: contiguous 1KB ds_read_b128, conflict-free ----
        s16x8 kf[4][2];
#pragma unroll
        for (int sj = 0; sj < 4; ++sj)
#pragma unroll
            for (int g = 0; g < 2; ++g)
                kf[sj][g] = *(const s16x8*)&Ks[p][(sj * 2 + g) * 512 + l * 8];

        // ---- QK (swapped): sc[mi][sj] = K-tile(sj) . Q(mi)^T ----
        f32x4 sc[2][4];
        __builtin_amdgcn_s_setprio(1);
#pragma unroll
        for (int sj = 0; sj < 4; ++sj)
#pragma unroll
            for (int mi = 0; mi < 2; ++mi) {
                sc[mi][sj] = MFMA(kf[sj][0], aq[mi][0], z);
                sc[mi][sj] = MFMA(kf[sj][1], aq[mi][1], sc[mi][sj]);
            }
        __builtin_amdgcn_s_setprio(0);

        // ---- exp2 + pack to PV A-frags fully in-register ----
        s16x8 ap[2][2];
#pragma unroll
        for (int mi = 0; mi < 2; ++mi) {
            float ex[4][4];
#pragma unroll
            for (int sj = 0; sj < 4; ++sj)
#pragma unroll
                for (int r = 0; r < 4; ++r)
                    ex[sj][r] = __builtin_amdgcn_exp2f(sc[mi][sj][r]);
#pragma unroll
            for (int g = 0; g < 2; ++g) {
                u32x4 pk;
                pk[0] = cvtpk(ex[2 * g][0],     ex[2 * g][1]);
                pk[1] = cvtpk(ex[2 * g][2],     ex[2 * g][3]);
                pk[2] = cvtpk(ex[2 * g + 1][0], ex[2 * g + 1][1]);
                pk[3] = cvtpk(ex[2 * g + 1][2], ex[2 * g + 1][3]);
                ap[mi][g] = __builtin_bit_cast(s16x8, pk);
            }
        }

        // ---- V fragment reads ----
        s16x8 vf[4][2];
#pragma unroll
        for (int nt = 0; nt < 4; ++nt)
#pragma unroll
            for (int g = 0; g < 2; ++g)
                vf[nt][g] = *(const s16x8*)&Vs[p][(nt * 2 + g) * 512 + l * 8];

        // ---- denominator (ones-column MFMA) + PV ----
        __builtin_amdgcn_s_setprio(1);
#pragma unroll
        for (int mi = 0; mi < 2; ++mi) {
            dnacc[mi] = MFMA(ap[mi][0], ones, dnacc[mi]);
            dnacc[mi] = MFMA(ap[mi][1], ones, dnacc[mi]);
        }
#pragma unroll
        for (int mi = 0; mi < 2; ++mi)
#pragma unroll
            for (int nt = 0; nt < 4; ++nt) {
                oacc[mi][nt] = MFMA(ap[mi][0], vf[nt][0], oacc[mi][nt]);
                oacc[mi][nt] = MFMA(ap[mi][1], vf[nt][1], oacc[mi][nt]);
            }
        __builtin_amdgcn_s_setprio(0);

        // next buffer must be fully landed before any wave reads it
        asm volatile("s_waitcnt vmcnt(0)" ::: "memory");
        __syncthreads();
    }

    // epilogue: dnacc row q=quad*4+r already holds the denominator for that q
#pragma unroll
    for (int mi = 0; mi < 2; ++mi)
#pragma unroll
        for (int r = 0; r < 4; ++r) {
            float inv = 1.0f / dnacc[mi][r];
            int t = qrow0 + mi * 16 + quad * 4 + r;
#pragma unroll
            for (int nt = 0; nt < 4; ++nt)
                ao[(size_t)(b * Tn + t) * Wd + h * Dh + nt * 16 + l16] =
                    f2bf(oacc[mi][nt][r] * inv);
        }
}

#define LSTR 40   // proj LDS row stride (80 B = 5*16: b128-aligned, 2-way banks)

// ---------------------------------------------------------------------------
// Projection GEMM, double-buffered + async reg-staged prefetch, 1 barrier/iter:
// out[4096][1024] = A(bf16)[M][K] @ Wb(bf16)[N][K]^T + bias, fp32 out.
// Block 256 = 4 waves; tile 128m x 64n x 32k; wave = 64m x 32n (8 MFMA/chunk).
// ---------------------------------------------------------------------------
__global__ __launch_bounds__(256, 2) void proj_gemm(
    const short* __restrict__ A, const short* __restrict__ Wb,
    const float* __restrict__ bias, float* __restrict__ out)
{
    __shared__ alignas(16) short As[2][128 * LSTR];
    __shared__ alignas(16) short Bs[2][64 * LSTR];

    const int tid  = threadIdx.x;
    const int w    = tid >> 6;
    const int l    = tid & 63;
    const int quad = l >> 4;
    const int l16  = l & 15;

    const int bn = blockIdx.x & 15;    // 16 n-tiles
    const int bm = blockIdx.x >> 4;    // 32 m-tiles
    const int m0 = bm * 128;
    const int n0 = bn * 64;
    const int wm = (w & 1) * 64;       // wave m-offset
    const int wn = (w >> 1) * 32;      // wave n-offset

    const int rr = tid >> 2;   // staging row 0..63
    const int sg = tid & 3;    // 16B segment 0..3 (BK=32 shorts = 64B row)

    f32x4 acc[4][2];
#pragma unroll
    for (int mi = 0; mi < 4; ++mi)
#pragma unroll
        for (int nt = 0; nt < 2; ++nt) {
            acc[mi][nt][0] = 0.f; acc[mi][nt][1] = 0.f;
            acc[mi][nt][2] = 0.f; acc[mi][nt][3] = 0.f;
        }

    // prologue: stage k-chunk 0 into buffer 0
    s16x8 ra0 = ld8(A  + (size_t)(m0 + rr) * Wd + sg * 8);
    s16x8 ra1 = ld8(A  + (size_t)(m0 + 64 + rr) * Wd + sg * 8);
    s16x8 rb  = ld8(Wb + (size_t)(n0 + rr) * Wd + sg * 8);
    *(s16x8*)&As[0][rr * LSTR + sg * 8]        = ra0;
    *(s16x8*)&As[0][(rr + 64) * LSTR + sg * 8] = ra1;
    *(s16x8*)&Bs[0][rr * LSTR + sg * 8]        = rb;
    __syncthreads();

    for (int k0 = 0; k0 < Wd; k0 += 32) {
        const int p = (k0 >> 5) & 1;

        if (k0 + 32 < Wd) {
            ra0 = ld8(A  + (size_t)(m0 + rr) * Wd + k0 + 32 + sg * 8);
            ra1 = ld8(A  + (size_t)(m0 + 64 + rr) * Wd + k0 + 32 + sg * 8);
            rb  = ld8(Wb + (size_t)(n0 + rr) * Wd + k0 + 32 + sg * 8);
        }

        s16x8 a[4], bw[2];
#pragma unroll
        for (int mi = 0; mi < 4; ++mi)
            a[mi] = *(const s16x8*)&As[p][(wm + mi * 16 + l16) * LSTR + quad * 8];
#pragma unroll
        for (int nt = 0; nt < 2; ++nt)
            bw[nt] = *(const s16x8*)&Bs[p][(wn + nt * 16 + l16) * LSTR + quad * 8];
        __builtin_amdgcn_s_setprio(1);
#pragma unroll
        for (int mi = 0; mi < 4; ++mi)
#pragma unroll
            for (int nt = 0; nt < 2; ++nt)
                acc[mi][nt] = MFMA(a[mi], bw[nt], acc[mi][nt]);
        __builtin_amdgcn_s_setprio(0);

        if (k0 + 32 < Wd) {
            *(s16x8*)&As[p ^ 1][rr * LSTR + sg * 8]        = ra0;
            *(s16x8*)&As[p ^ 1][(rr + 64) * LSTR + sg * 8] = ra1;
            *(s16x8*)&Bs[p ^ 1][rr * LSTR + sg * 8]        = rb;
        }
        __syncthreads();
    }

#pragma unroll
    for (int nt = 0; nt < 2; ++nt) {
        float bv = bias[n0 + wn + nt * 16 + l16];
#pragma unroll
        for (int mi = 0; mi < 4; ++mi)
#pragma unroll
            for (int r = 0; r < 4; ++r)
                out[(size_t)(m0 + wm + mi * 16 + quad * 4 + r) * Wd + n0 + wn + nt * 16 + l16] =
                    acc[mi][nt][r] + bv;
    }
}

extern "C" void kernel_launch(void* const* d_in, const int* in_sizes, int n_in,
                              void* d_out, int out_size, void* d_ws, size_t ws_size,
                              hipStream_t stream) {
    const float* x  = (const float*)d_in[0];   // [2,2048,1024] fp32
    const float* ck = (const float*)d_in[1];   // [2,2048,1024] fp32
    const float* cv = (const float*)d_in[2];   // [2,2048,1024] fp32
    const float* wp = (const float*)d_in[3];   // [1024,1024]   fp32
    const float* bp = (const float*)d_in[4];   // [1024]        fp32

    const int nX = Bn * Tn * Wd;   // 4,194,304
    const int nW = Wd * Wd;        // 1,048,576

    short* kpb = (short*)d_ws;     // 8 MB  (K, MFMA A-frag packed)
    short* vpb = kpb + nX;         // 8 MB  (V^T, MFMA B-frag packed + s-perm)
    short* wbb = vpb + nX;         // 2 MB  (Wp bf16)
    short* am  = wbb + nW;         // 8 MB  (attention output, bf16)

    prep<<<dim3(2048 + nW / 2048), dim3(256), 0, stream>>>(ck, cv, wp, kpb, vpb, wbb);

    attn_fused<<<dim3(Bn * Hn * (Tn / 128)), dim3(256), 0, stream>>>(x, kpb, vpb, am);
    proj_gemm<<<dim3((Bn * Tn / 128) * (Wd / 64)), dim3(256), 0, stream>>>(
        am, wbb, bp, (float*)d_out);
}